// Round 7
// baseline (627.892 us; speedup 1.0000x reference)
//
#include <hip/hip_runtime.h>
#include <cmath>

// PSNR + 3D-SSIM, pred/gt (N=4, C=16->D, H=512, W=512) f32.
// R15 = R11 (best measured: 158us fused, dot2 blurs, verified) + the two
// fixes its counters demand:
//  1) XCD-aware bijective block swizzle (4096%8==0): 512 consecutive tiles
//     per XCD -> halo re-reads hit the XCD-local L2 instead of crossing
//     XCDs (R11-R14 all fetch 1.9x input at ~1.3-1.6 TB/s; dur ~= FETCH/BW).
//  2) 64-f32 D-accumulators -> f16 slice-pair history (32 regs, statically
//     indexed via full 8x2 unroll); D-blur = 512 amortized dot2 in the
//     epilogue with renorm'd f16 pair weights (R10's idea, without R10's
//     impossible register fit). ~100 regs under a (256,4) cap=128 ->
//     16 waves/CU (50%) vs R11's 12 (29.8%), and -32 VALU/thread/slice.
// Everything else (layouts, H/W dot2 bodies, barriers, PSNR) verbatim R11.

#define NB 4
#define DD 16
#define HH 512
#define WW 512
#define SLICE (HH * WW)
#define VOL (DD * SLICE)
#define C1F 0.0001f
#define C2F 0.0009f

#define TH 16
#define TW 16
#define SCOLS 26            // staged cols (TW+10)
#define NRP 13              // staged row-pairs ((TH+10)/2)
#define PW 14               // uint4 words per col-parity plane (13 + pad)
#define PLSTR 28            // row-pair stride (2 planes)
#define SDW (NRP * PLSTR)   // 364 uint4 = 5824 B
#define TMW (TH * PW)       // 224 uint4 = 3584 B
#define NTHR 256
#define SIT (NRP * SCOLS)   // 338 stage items per slice
#define XTRA (SIT - NTHR)   // 82
#define HITEMS 104          // 8 out-row-pairs x 13 col-pairs

typedef _Float16 h2v __attribute__((ext_vector_type(2)));

struct KArg {
  unsigned ge[6], go[6];   // f16x2 tap-pair coeffs, even/odd phase (renorm'd)
  unsigned w2[128];        // [dout][m] = f16x2 (wl[2m][dout], wl[2m+1][dout])
};

__device__ inline float dot2h(unsigned a, unsigned b, float c) {
#if __has_builtin(__builtin_amdgcn_fdot2)
  return __builtin_amdgcn_fdot2(__builtin_bit_cast(h2v, a),
                                __builtin_bit_cast(h2v, b), c, false);
#else
  h2v av = __builtin_bit_cast(h2v, a), bv = __builtin_bit_cast(h2v, b);
  return fmaf((float)av.y, (float)bv.y, fmaf((float)av.x, (float)bv.x, c));
#endif
}
__device__ inline unsigned pkh(float a, float b) {
  return __builtin_bit_cast(unsigned, __builtin_amdgcn_cvt_pkrtz(a, b));
}
__device__ inline int iclamp(int v, int lo, int hi) {
  return v < lo ? lo : (v > hi ? hi : v);
}

__device__ inline float block_sum256(float v) {
#pragma unroll
  for (int o = 32; o > 0; o >>= 1) v += __shfl_down(v, o, 64);
  __shared__ float r[4];
  if ((threadIdx.x & 63) == 0) r[threadIdx.x >> 6] = v;
  __syncthreads();
  float out = 0.f;
  if (threadIdx.x == 0) {
#pragma unroll
    for (int i = 0; i < 4; ++i) out += r[i];
  }
  __syncthreads();
  return out;
}

__global__ void zero_acc_k(float* acc) {
  if (threadIdx.x < 8) acc[threadIdx.x] = 0.f;
}

__global__ __launch_bounds__(NTHR, 4) void fused_k(
    const float* __restrict__ pred, const float* __restrict__ gt,
    float* __restrict__ acc, KArg ka) {
  __shared__ uint4 sd[SDW];    // single-buffered staged slice
  __shared__ uint4 tmp[TMW];   // H-blurred

  // XCD-aware bijective swizzle: 4096 blocks, 512-chunk per XCD
  int b0 = blockIdx.x;
  int b = (b0 & 7) * ((NB * 1024) >> 3) + (b0 >> 3);
  int tile = b & 1023;               // 32 h-tiles x 32 w-tiles
  int n = b >> 10;
  int th0 = (tile >> 5) * TH;
  int tw0 = (tile & 31) * TW;
  int t = threadIdx.x;

  // ---- stage metadata, slot 0 (item t, always < 338)
  int rp0 = t / SCOLS, x0 = t - rp0 * SCOLS;
  int gx0 = iclamp(tw0 + x0 - 5, 0, WW - 1);
  int go0a = iclamp(th0 + 2 * rp0 - 5, 0, HH - 1) * WW + gx0;
  int go0b = iclamp(th0 + 2 * rp0 - 4, 0, HH - 1) * WW + gx0;
  int w0i = (2 * rp0 + (x0 & 1)) * PW + (x0 >> 1);
  bool ox0 = (x0 >= 5) && (x0 < 5 + TW);
  float o0a = (ox0 && rp0 >= 3 && rp0 <= 10) ? 1.f : 0.f;
  float o0b = (ox0 && rp0 >= 2 && rp0 <= 9) ? 1.f : 0.f;
  // slot 1 (items 256..337 -> threads 174..255)
  int i1 = t + XTRA;
  bool has2 = (i1 >= NTHR);
  int rp1 = i1 / SCOLS, x1 = i1 - rp1 * SCOLS;
  int gx1 = iclamp(tw0 + x1 - 5, 0, WW - 1);
  int go1a = iclamp(th0 + 2 * rp1 - 5, 0, HH - 1) * WW + gx1;
  int go1b = iclamp(th0 + 2 * rp1 - 4, 0, HH - 1) * WW + gx1;
  int w1i = (2 * rp1 + (x1 & 1)) * PW + (x1 >> 1);
  bool ox1 = (x1 >= 5) && (x1 < 5 + TW);
  float o1a = (ox1 && rp1 >= 3 && rp1 <= 10) ? 1.f : 0.f;
  float o1b = (ox1 && rp1 >= 2 && rp1 <= 9) ? 1.f : 0.f;

  // ---- H metadata: item = (out-row-pair hm, col-pair hcp), m-minor
  bool hasH = (t < HITEMS);
  int hm = t & 7, hcp = t >> 3;
  int hrd = hm * PLSTR + hcp;        // plane0 read base (tap J adds J*PLSTR)
  int hwr = (2 * hm) * PW + hcp;     // row 2m write (+PW for row 2m+1)

  // ---- W metadata: thread owns px (t>>4, t&15)
  int wx = t & 15;
  int wrd = (t >> 4) * PW + (wx >> 1);
  unsigned cw[6];
#pragma unroll
  for (int J = 0; J < 6; ++J) cw[J] = (wx & 1) ? ka.go[J] : ka.ge[J];

  const float* pb = pred + (size_t)n * VOL;
  const float* qb = gt + (size_t)n * VOL;

  // prefetch slice 0
  float p0a = pb[go0a], p0b = pb[go0b], q0a = qb[go0a], q0b = qb[go0b];
  float p1a = 0.f, p1b = 0.f, q1a = 0.f, q1b = 0.f;
  if (has2) { p1a = pb[go1a]; p1b = pb[go1b]; q1a = qb[go1a]; q1b = qb[go1b]; }

  float psnr = 0.f;
  unsigned h0[8], h1[8], h2[8], h3[8];   // f16 slice-pair history per channel

// One slice, verbatim R11 body; leaves W-blur results in ww0..ww3.
#define DO_SLICE(D)                                                         \
  {                                                                         \
    float SA = p0a + q0a, DA = p0a - q0a;                                   \
    float SB = p0b + q0b, DB = p0b - q0b;                                   \
    float dA = DA * DA, dB = DB * DB;                                       \
    psnr = fmaf(o0a, dA, psnr);                                             \
    psnr = fmaf(o0b, dB, psnr);                                             \
    sd[w0i] = make_uint4(pkh(SA, SB), pkh(DA, DB),                          \
                         pkh(SA * SA, SB * SB), pkh(dA, dB));               \
  }                                                                         \
  if (has2) {                                                               \
    float SA = p1a + q1a, DA = p1a - q1a;                                   \
    float SB = p1b + q1b, DB = p1b - q1b;                                   \
    float dA = DA * DA, dB = DB * DB;                                       \
    psnr = fmaf(o1a, dA, psnr);                                             \
    psnr = fmaf(o1b, dB, psnr);                                             \
    sd[w1i] = make_uint4(pkh(SA, SB), pkh(DA, DB),                          \
                         pkh(SA * SA, SB * SB), pkh(dA, dB));               \
  }                                                                         \
  __syncthreads(); /* B1: sd ready; fences tmp vs prev W reads */           \
  if ((D) < DD - 1) {                                                       \
    const float* P = pb + (size_t)((D) + 1) * SLICE;                        \
    const float* Q = qb + (size_t)((D) + 1) * SLICE;                        \
    p0a = P[go0a]; p0b = P[go0b]; q0a = Q[go0a]; q0b = Q[go0b];             \
    if (has2) { p1a = P[go1a]; p1b = P[go1b]; q1a = Q[go1a]; q1b = Q[go1b]; } \
  }                                                                         \
  if (hasH) {                                                               \
    float e0[4] = {0, 0, 0, 0}, e1[4] = {0, 0, 0, 0};                       \
    float r0[4] = {0, 0, 0, 0}, r1[4] = {0, 0, 0, 0};                       \
    _Pragma("unroll")                                                       \
    for (int J = 0; J < 6; ++J) {                                           \
      uint4 ve = sd[hrd + J * PLSTR];                                       \
      uint4 vo = sd[hrd + J * PLSTR + PW];                                  \
      unsigned cge = ka.ge[J], cgo = ka.go[J];                              \
      e0[0] = dot2h(cge, ve.x, e0[0]); e0[1] = dot2h(cge, ve.y, e0[1]);     \
      e0[2] = dot2h(cge, ve.z, e0[2]); e0[3] = dot2h(cge, ve.w, e0[3]);     \
      r0[0] = dot2h(cgo, ve.x, r0[0]); r0[1] = dot2h(cgo, ve.y, r0[1]);     \
      r0[2] = dot2h(cgo, ve.z, r0[2]); r0[3] = dot2h(cgo, ve.w, r0[3]);     \
      e1[0] = dot2h(cge, vo.x, e1[0]); e1[1] = dot2h(cge, vo.y, e1[1]);     \
      e1[2] = dot2h(cge, vo.z, e1[2]); e1[3] = dot2h(cge, vo.w, e1[3]);     \
      r1[0] = dot2h(cgo, vo.x, r1[0]); r1[1] = dot2h(cgo, vo.y, r1[1]);     \
      r1[2] = dot2h(cgo, vo.z, r1[2]); r1[3] = dot2h(cgo, vo.w, r1[3]);     \
    }                                                                       \
    tmp[hwr] = make_uint4(pkh(e0[0], e1[0]), pkh(e0[1], e1[1]),             \
                          pkh(e0[2], e1[2]), pkh(e0[3], e1[3]));            \
    tmp[hwr + PW] = make_uint4(pkh(r0[0], r1[0]), pkh(r0[1], r1[1]),        \
                               pkh(r0[2], r1[2]), pkh(r0[3], r1[3]));       \
  }                                                                         \
  __syncthreads(); /* B2: tmp ready; separates sd reads from next stage */  \
  ww0 = 0.f; ww1 = 0.f; ww2 = 0.f; ww3 = 0.f;                               \
  _Pragma("unroll")                                                         \
  for (int J = 0; J < 6; ++J) {                                             \
    uint4 v = tmp[wrd + J];                                                 \
    ww0 = dot2h(cw[J], v.x, ww0); ww1 = dot2h(cw[J], v.y, ww1);             \
    ww2 = dot2h(cw[J], v.z, ww2); ww3 = dot2h(cw[J], v.w, ww3);             \
  }

  float ww0, ww1, ww2, ww3;
#pragma unroll
  for (int m = 0; m < 8; ++m) {
    float oe0, oe1, oe2, oe3;
    DO_SLICE(2 * m)                  // even slice: hold in f32 temps
    oe0 = ww0; oe1 = ww1; oe2 = ww2; oe3 = ww3;
    DO_SLICE(2 * m + 1)              // odd slice: pack pair into history
    h0[m] = pkh(oe0, ww0);
    h1[m] = pkh(oe1, ww1);
    h2[m] = pkh(oe2, ww2);
    h3[m] = pkh(oe3, ww3);
  }
#undef DO_SLICE

  // ---- D-blur (dot2 over slice-pair history) + SSIM per dout
  float ssum = 0.f;
#pragma unroll
  for (int o = 0; o < DD; ++o) {
    float A0 = 0.f, A1 = 0.f, A2 = 0.f, A3 = 0.f;
#pragma unroll
    for (int m = 0; m < 8; ++m) {
      unsigned c = ka.w2[o * 8 + m];
      A0 = dot2h(c, h0[m], A0);
      A1 = dot2h(c, h1[m], A1);
      A2 = dot2h(c, h2[m], A2);
      A3 = dot2h(c, h3[m], A3);
    }
    float SS = A0 * A0, DDm = A1 * A1;
    float m12_2 = (SS - DDm) * 0.5f;     // 2*mu1*mu2
    float msq   = (SS + DDm) * 0.5f;     // mu1^2 + mu2^2
    float Epq   = (A2 - A3) * 0.25f;     // E[pq]
    float Esum  = (A2 + A3) * 0.5f;      // E[p^2+q^2]
    float sig12_2 = 2.f * Epq - m12_2;   // 2*sigma12
    float svar    = Esum - msq;          // sigma1^2 + sigma2^2
    float num = (m12_2 + C1F) * (sig12_2 + C2F);
    float den = (msq + C1F) * (svar + C2F);
    ssum += num / den;
  }
  float bs = block_sum256(ssum);
  if (t == 0) atomicAdd(&acc[4 + n], bs);
  float bp = block_sum256(psnr);
  if (t == 0) atomicAdd(&acc[n], bp);
}

__global__ void final_k(const float* __restrict__ acc, float* __restrict__ out) {
  if (threadIdx.x == 0 && blockIdx.x == 0) {
    double psnr = 0.0, ssim = 0.0;
    for (int n = 0; n < NB; ++n) {
      double mse = (double)acc[n] / (double)VOL;
      psnr += 10.0 * log10(1.0 / mse);
      ssim += (double)acc[4 + n] / (double)VOL;
    }
    out[0] = (float)psnr;
    out[1] = (float)ssim;
    out[2] = (float)NB;
  }
}

// host f32 -> f16 (RNE)
static unsigned short f2h(float f) {
  union { float f; unsigned u; } v; v.f = f;
  unsigned u = v.u;
  unsigned s = (u >> 16) & 0x8000u;
  int e = (int)((u >> 23) & 0xff) - 127 + 15;
  unsigned m = u & 0x7fffffu;
  if (e <= 0) return (unsigned short)s;
  if (e >= 31) return (unsigned short)(s | 0x7c00u);
  unsigned h = ((unsigned)e << 10) | (m >> 13);
  unsigned rem = m & 0x1fffu;
  if (rem > 0x1000u || (rem == 0x1000u && (h & 1u))) h++;
  return (unsigned short)(s | h);
}
// host f16 -> f32 (normals + zero)
static float h2f(unsigned short h) {
  unsigned se = (h >> 10) & 0x1f, m = h & 0x3ffu, s = ((unsigned)h & 0x8000u) << 16;
  union { unsigned u; float f; } v;
  if (se == 0) { v.u = s; return v.f; }
  v.u = s | ((se - 15 + 127) << 23) | (m << 13);
  return v.f;
}

extern "C" void kernel_launch(void* const* d_in, const int* in_sizes, int n_in,
                              void* d_out, int out_size, void* d_ws, size_t ws_size,
                              hipStream_t stream) {
  const float* pred = (const float*)d_in[0];
  const float* gt = (const float*)d_in[1];
  float* acc = (float*)d_ws;    // 8 floats

  double tt[11], s = 0.0;
  for (int i = 0; i < 11; ++i) {
    double x = i - 5;
    tt[i] = exp(-(x * x) / 4.5);
    s += tt[i];
  }
  float g[11];
  for (int i = 0; i < 11; ++i) g[i] = (float)(tt[i] / s);

  // f16 taps renormalized so the f16 values sum exactly to 1
  unsigned short hg[11];
  for (int i = 0; i < 11; ++i) hg[i] = f2h(g[i]);
  for (int pass = 0; pass < 3; ++pass) {
    double sum = 0.0;
    for (int i = 0; i < 11; ++i) sum += (double)h2f(hg[i]);
    hg[5] = f2h((float)((double)h2f(hg[5]) + (1.0 - sum)));
  }

  KArg ka;
  // even phase: (g0,g1)(g2,g3)(g4,g5)(g6,g7)(g8,g9)(g10,0)
  for (int j = 0; j < 5; ++j)
    ka.ge[j] = (unsigned)hg[2 * j] | ((unsigned)hg[2 * j + 1] << 16);
  ka.ge[5] = (unsigned)hg[10];
  // odd phase: (0,g0)(g1,g2)(g3,g4)(g5,g6)(g7,g8)(g9,g10)
  ka.go[0] = ((unsigned)hg[0]) << 16;
  for (int j = 1; j < 6; ++j)
    ka.go[j] = (unsigned)hg[2 * j - 1] | ((unsigned)hg[2 * j] << 16);

  // clamp-folded D-blur weights wl[d][dout]; per-dout f16 renorm, pair-packed
  float wl[DD][DD];
  for (int o = 0; o < DD; ++o)
    for (int d = 0; d < DD; ++d) {
      float w = 0.f;
      for (int k = 0; k < 11; ++k) {
        int j = o + k - 5;
        j = j < 0 ? 0 : (j > 15 ? 15 : j);
        if (j == d) w += g[k];
      }
      wl[d][o] = w;
    }
  for (int o = 0; o < DD; ++o) {
    unsigned short wv[DD];
    int dmx = 0;
    for (int d = 0; d < DD; ++d) {
      wv[d] = f2h(wl[d][o]);
      if (wl[d][o] > wl[dmx][o]) dmx = d;
    }
    for (int pass = 0; pass < 3; ++pass) {
      double sum = 0.0;
      for (int d = 0; d < DD; ++d) sum += (double)h2f(wv[d]);
      wv[dmx] = f2h((float)((double)h2f(wv[dmx]) + (1.0 - sum)));
    }
    for (int m = 0; m < 8; ++m)
      ka.w2[o * 8 + m] = (unsigned)wv[2 * m] | ((unsigned)wv[2 * m + 1] << 16);
  }

  zero_acc_k<<<1, 64, 0, stream>>>(acc);
  fused_k<<<NB * 1024, NTHR, 0, stream>>>(pred, gt, acc, ka);
  final_k<<<1, 1, 0, stream>>>(acc, (float*)d_out);
}

// Round 8
// 252.399 us; speedup vs baseline: 2.4877x; 2.4877x over previous
//
#include <hip/hip_runtime.h>
#include <cmath>

// PSNR + 3D-SSIM, pred/gt (N=4, C=16->D, H=512, W=512) f32.
// R16 = R11 byte-for-byte (best measured: 158us fused, no spill) + ONE
// change: bijective XCD-aware block swizzle (4096%8==0). Each XCD owns 512
// consecutive tiles (contiguous half-image of one n); per-slice working set
// ~1MB << 4MB XCD L2, so the 1.93x halo re-fetch becomes L2-local.
// R15 tried this + a register restructure under a (256,4) cap and spilled
// (974MB scratch) -- the swizzle itself was never tested. This round tests
// exactly that one variable.

#define NB 4
#define DD 16
#define HH 512
#define WW 512
#define SLICE (HH * WW)
#define VOL (DD * SLICE)
#define C1F 0.0001f
#define C2F 0.0009f

#define TH 16
#define TW 16
#define SCOLS 26            // staged cols (TW+10)
#define NRP 13              // staged row-pairs ((TH+10)/2)
#define PW 14               // uint4 words per col-parity plane (13 + pad)
#define PLSTR 28            // row-pair stride (2 planes)
#define SDW (NRP * PLSTR)   // 364 uint4 = 5824 B
#define TMW (TH * PW)       // 224 uint4 = 3584 B
#define NTHR 256
#define SIT (NRP * SCOLS)   // 338 stage items per slice
#define XTRA (SIT - NTHR)   // 82
#define HITEMS 104          // 8 out-row-pairs x 13 col-pairs

typedef _Float16 h2v __attribute__((ext_vector_type(2)));

struct KArg {
  unsigned ge[6], go[6];   // f16x2 tap-pair coeffs, even/odd phase (renorm'd)
  float wlT[DD * DD];      // wlT[d*16+dout] = clamp-folded D weight (f32)
};

__device__ inline float dot2h(unsigned a, unsigned b, float c) {
#if __has_builtin(__builtin_amdgcn_fdot2)
  return __builtin_amdgcn_fdot2(__builtin_bit_cast(h2v, a),
                                __builtin_bit_cast(h2v, b), c, false);
#else
  h2v av = __builtin_bit_cast(h2v, a), bv = __builtin_bit_cast(h2v, b);
  return fmaf((float)av.y, (float)bv.y, fmaf((float)av.x, (float)bv.x, c));
#endif
}
__device__ inline unsigned pkh(float a, float b) {
  return __builtin_bit_cast(unsigned, __builtin_amdgcn_cvt_pkrtz(a, b));
}
__device__ inline int iclamp(int v, int lo, int hi) {
  return v < lo ? lo : (v > hi ? hi : v);
}

__device__ inline float block_sum256(float v) {
#pragma unroll
  for (int o = 32; o > 0; o >>= 1) v += __shfl_down(v, o, 64);
  __shared__ float r[4];
  if ((threadIdx.x & 63) == 0) r[threadIdx.x >> 6] = v;
  __syncthreads();
  float out = 0.f;
  if (threadIdx.x == 0) {
#pragma unroll
    for (int i = 0; i < 4; ++i) out += r[i];
  }
  __syncthreads();
  return out;
}

__global__ void zero_acc_k(float* acc) {
  if (threadIdx.x < 8) acc[threadIdx.x] = 0.f;
}

__global__ __launch_bounds__(NTHR, 3) void fused_k(
    const float* __restrict__ pred, const float* __restrict__ gt,
    float* __restrict__ acc, KArg ka) {
  __shared__ uint4 sd[SDW];    // single-buffered staged slice
  __shared__ uint4 tmp[TMW];   // H-blurred

  // XCD-aware bijective swizzle (the ONE change vs R11)
  int b0 = blockIdx.x;
  int b = (b0 & 7) * ((NB * 1024) >> 3) + (b0 >> 3);
  int tile = b & 1023;               // 32 h-tiles x 32 w-tiles
  int n = b >> 10;
  int th0 = (tile >> 5) * TH;
  int tw0 = (tile & 31) * TW;
  int t = threadIdx.x;

  // ---- stage metadata, slot 0 (item t, always < 338)
  int rp0 = t / SCOLS, x0 = t - rp0 * SCOLS;
  int gx0 = iclamp(tw0 + x0 - 5, 0, WW - 1);
  int go0a = iclamp(th0 + 2 * rp0 - 5, 0, HH - 1) * WW + gx0;
  int go0b = iclamp(th0 + 2 * rp0 - 4, 0, HH - 1) * WW + gx0;
  int w0i = (2 * rp0 + (x0 & 1)) * PW + (x0 >> 1);
  bool ox0 = (x0 >= 5) && (x0 < 5 + TW);
  float o0a = (ox0 && rp0 >= 3 && rp0 <= 10) ? 1.f : 0.f;  // row 2rp-5 owned
  float o0b = (ox0 && rp0 >= 2 && rp0 <= 9) ? 1.f : 0.f;   // row 2rp-4 owned
  // slot 1 (items 256..337 -> threads 174..255)
  int i1 = t + XTRA;
  bool has2 = (i1 >= NTHR);
  int rp1 = i1 / SCOLS, x1 = i1 - rp1 * SCOLS;
  int gx1 = iclamp(tw0 + x1 - 5, 0, WW - 1);
  int go1a = iclamp(th0 + 2 * rp1 - 5, 0, HH - 1) * WW + gx1;
  int go1b = iclamp(th0 + 2 * rp1 - 4, 0, HH - 1) * WW + gx1;
  int w1i = (2 * rp1 + (x1 & 1)) * PW + (x1 >> 1);
  bool ox1 = (x1 >= 5) && (x1 < 5 + TW);
  float o1a = (ox1 && rp1 >= 3 && rp1 <= 10) ? 1.f : 0.f;
  float o1b = (ox1 && rp1 >= 2 && rp1 <= 9) ? 1.f : 0.f;

  // ---- H metadata: item = (out-row-pair hm, col-pair hcp), m-minor
  bool hasH = (t < HITEMS);
  int hm = t & 7, hcp = t >> 3;
  int hrd = hm * PLSTR + hcp;        // plane0 read base (tap J adds J*PLSTR)
  int hwr = (2 * hm) * PW + hcp;     // row 2m write (+PW for row 2m+1)

  // ---- W metadata: thread owns px (t>>4, t&15)
  int wx = t & 15;
  int wrd = (t >> 4) * PW + (wx >> 1);
  unsigned cw[6];
#pragma unroll
  for (int J = 0; J < 6; ++J) cw[J] = (wx & 1) ? ka.go[J] : ka.ge[J];

  const float* pb = pred + (size_t)n * VOL;
  const float* qb = gt + (size_t)n * VOL;

  // prefetch slice 0
  float p0a = pb[go0a], p0b = pb[go0b], q0a = qb[go0a], q0b = qb[go0b];
  float p1a = 0.f, p1b = 0.f, q1a = 0.f, q1b = 0.f;
  if (has2) { p1a = pb[go1a]; p1b = pb[go1b]; q1a = qb[go1a]; q1b = qb[go1b]; }

  float psnr = 0.f;
  float a0[DD], a1[DD], a2[DD], a3[DD];
#pragma unroll
  for (int j = 0; j < DD; ++j) { a0[j] = a1[j] = a2[j] = a3[j] = 0.f; }

#pragma unroll 1
  for (int d = 0; d < DD; ++d) {
    // ---- stage slice d (f16 row-pair packed, AoS uint4)
    {
      float SA = p0a + q0a, DA = p0a - q0a;
      float SB = p0b + q0b, DB = p0b - q0b;
      float dA = DA * DA, dB = DB * DB;
      psnr = fmaf(o0a, dA, psnr);
      psnr = fmaf(o0b, dB, psnr);
      sd[w0i] = make_uint4(pkh(SA, SB), pkh(DA, DB),
                           pkh(SA * SA, SB * SB), pkh(dA, dB));
    }
    if (has2) {
      float SA = p1a + q1a, DA = p1a - q1a;
      float SB = p1b + q1b, DB = p1b - q1b;
      float dA = DA * DA, dB = DB * DB;
      psnr = fmaf(o1a, dA, psnr);
      psnr = fmaf(o1b, dB, psnr);
      sd[w1i] = make_uint4(pkh(SA, SB), pkh(DA, DB),
                           pkh(SA * SA, SB * SB), pkh(dA, dB));
    }
    __syncthreads();   // B1: sd ready; also fences tmp vs prev iter's W reads

    // prefetch slice d+1 (hides under H+W; consumed next iter after B2+W)
    if (d < DD - 1) {
      const float* P = pb + (size_t)(d + 1) * SLICE;
      const float* Q = qb + (size_t)(d + 1) * SLICE;
      p0a = P[go0a]; p0b = P[go0b]; q0a = Q[go0a]; q0b = Q[go0b];
      if (has2) { p1a = P[go1a]; p1b = P[go1b]; q1a = Q[go1a]; q1b = Q[go1b]; }
    }

    // ---- H-blur (vertical), fused row parities: 12 b128 reads -> 2 writes
    if (hasH) {
      float e0[4] = {0, 0, 0, 0}, e1[4] = {0, 0, 0, 0};   // row 2m, col 2cp / 2cp+1
      float r0[4] = {0, 0, 0, 0}, r1[4] = {0, 0, 0, 0};   // row 2m+1
#pragma unroll
      for (int J = 0; J < 6; ++J) {
        uint4 ve = sd[hrd + J * PLSTR];        // col 2cp,  row-pair m+J
        uint4 vo = sd[hrd + J * PLSTR + PW];   // col 2cp+1
        unsigned cge = ka.ge[J], cgo = ka.go[J];
        e0[0] = dot2h(cge, ve.x, e0[0]); e0[1] = dot2h(cge, ve.y, e0[1]);
        e0[2] = dot2h(cge, ve.z, e0[2]); e0[3] = dot2h(cge, ve.w, e0[3]);
        r0[0] = dot2h(cgo, ve.x, r0[0]); r0[1] = dot2h(cgo, ve.y, r0[1]);
        r0[2] = dot2h(cgo, ve.z, r0[2]); r0[3] = dot2h(cgo, ve.w, r0[3]);
        e1[0] = dot2h(cge, vo.x, e1[0]); e1[1] = dot2h(cge, vo.y, e1[1]);
        e1[2] = dot2h(cge, vo.z, e1[2]); e1[3] = dot2h(cge, vo.w, e1[3]);
        r1[0] = dot2h(cgo, vo.x, r1[0]); r1[1] = dot2h(cgo, vo.y, r1[1]);
        r1[2] = dot2h(cgo, vo.z, r1[2]); r1[3] = dot2h(cgo, vo.w, r1[3]);
      }
      tmp[hwr] = make_uint4(pkh(e0[0], e1[0]), pkh(e0[1], e1[1]),
                            pkh(e0[2], e1[2]), pkh(e0[3], e1[3]));
      tmp[hwr + PW] = make_uint4(pkh(r0[0], r1[0]), pkh(r0[1], r1[1]),
                                 pkh(r0[2], r1[2]), pkh(r0[3], r1[3]));
    }
    __syncthreads();   // B2: tmp ready; also separates H's sd reads from the
                       // NEXT iteration's stage writes (single buffer safe)

    // ---- W-blur at owned px: 6 b128 reads (2-way broadcast), 24 dot2
    float w0 = 0.f, w1 = 0.f, w2 = 0.f, w3 = 0.f;
#pragma unroll
    for (int J = 0; J < 6; ++J) {
      uint4 v = tmp[wrd + J];
      w0 = dot2h(cw[J], v.x, w0); w1 = dot2h(cw[J], v.y, w1);
      w2 = dot2h(cw[J], v.z, w2); w3 = dot2h(cw[J], v.w, w3);
    }
    // ---- D-accumulate (f32, weights uniform -> s_load + v_fma)
    const float* wl = ka.wlT + d * DD;
#pragma unroll
    for (int o = 0; o < DD; ++o) {
      float w = wl[o];
      a0[o] = fmaf(w, w0, a0[o]);
      a1[o] = fmaf(w, w1, a1[o]);
      a2[o] = fmaf(w, w2, a2[o]);
      a3[o] = fmaf(w, w3, a3[o]);
    }
  }

  // ---- SSIM over the 16 douts of this px
  float ssum = 0.f;
#pragma unroll
  for (int j = 0; j < DD; ++j) {
    float Sb = a0[j], Db = a1[j], B1 = a2[j], B2 = a3[j];
    float SS = Sb * Sb, DDm = Db * Db;
    float m12_2 = (SS - DDm) * 0.5f;     // 2*mu1*mu2
    float msq   = (SS + DDm) * 0.5f;     // mu1^2 + mu2^2
    float Epq   = (B1 - B2) * 0.25f;     // E[pq]
    float Esum  = (B1 + B2) * 0.5f;      // E[p^2+q^2]
    float sig12_2 = 2.f * Epq - m12_2;   // 2*sigma12
    float svar    = Esum - msq;          // sigma1^2 + sigma2^2
    float num = (m12_2 + C1F) * (sig12_2 + C2F);
    float den = (msq + C1F) * (svar + C2F);
    ssum += num / den;
  }
  float bs = block_sum256(ssum);
  if (t == 0) atomicAdd(&acc[4 + n], bs);
  float bp = block_sum256(psnr);
  if (t == 0) atomicAdd(&acc[n], bp);
}

__global__ void final_k(const float* __restrict__ acc, float* __restrict__ out) {
  if (threadIdx.x == 0 && blockIdx.x == 0) {
    double psnr = 0.0, ssim = 0.0;
    for (int n = 0; n < NB; ++n) {
      double mse = (double)acc[n] / (double)VOL;
      psnr += 10.0 * log10(1.0 / mse);
      ssim += (double)acc[4 + n] / (double)VOL;
    }
    out[0] = (float)psnr;
    out[1] = (float)ssim;
    out[2] = (float)NB;
  }
}

// host f32 -> f16 (round-to-nearest-even)
static unsigned short f2h(float f) {
  union { float f; unsigned u; } v; v.f = f;
  unsigned u = v.u;
  unsigned s = (u >> 16) & 0x8000u;
  int e = (int)((u >> 23) & 0xff) - 127 + 15;
  unsigned m = u & 0x7fffffu;
  if (e <= 0) return (unsigned short)s;
  if (e >= 31) return (unsigned short)(s | 0x7c00u);
  unsigned h = ((unsigned)e << 10) | (m >> 13);
  unsigned rem = m & 0x1fffu;
  if (rem > 0x1000u || (rem == 0x1000u && (h & 1u))) h++;
  return (unsigned short)(s | h);
}
// host f16 -> f32 (normals + zero)
static float h2f(unsigned short h) {
  unsigned se = (h >> 10) & 0x1f, m = h & 0x3ffu, s = ((unsigned)h & 0x8000u) << 16;
  union { unsigned u; float f; } v;
  if (se == 0) { v.u = s; return v.f; }
  v.u = s | ((se - 15 + 127) << 23) | (m << 13);
  return v.f;
}

extern "C" void kernel_launch(void* const* d_in, const int* in_sizes, int n_in,
                              void* d_out, int out_size, void* d_ws, size_t ws_size,
                              hipStream_t stream) {
  const float* pred = (const float*)d_in[0];
  const float* gt = (const float*)d_in[1];
  float* acc = (float*)d_ws;    // 8 floats

  double tt[11], s = 0.0;
  for (int i = 0; i < 11; ++i) {
    double x = i - 5;
    tt[i] = exp(-(x * x) / 4.5);
    s += tt[i];
  }
  float g[11];
  for (int i = 0; i < 11; ++i) g[i] = (float)(tt[i] / s);

  // f16 taps renormalized so the f16 values sum exactly to 1
  unsigned short hg[11];
  for (int i = 0; i < 11; ++i) hg[i] = f2h(g[i]);
  for (int pass = 0; pass < 3; ++pass) {
    double sum = 0.0;
    for (int i = 0; i < 11; ++i) sum += (double)h2f(hg[i]);
    hg[5] = f2h((float)((double)h2f(hg[5]) + (1.0 - sum)));
  }

  KArg ka;
  // even phase: (g0,g1)(g2,g3)(g4,g5)(g6,g7)(g8,g9)(g10,0)
  for (int j = 0; j < 5; ++j)
    ka.ge[j] = (unsigned)hg[2 * j] | ((unsigned)hg[2 * j + 1] << 16);
  ka.ge[5] = (unsigned)hg[10];
  // odd phase: (0,g0)(g1,g2)(g3,g4)(g5,g6)(g7,g8)(g9,g10)
  ka.go[0] = ((unsigned)hg[0]) << 16;
  for (int j = 1; j < 6; ++j)
    ka.go[j] = (unsigned)hg[2 * j - 1] | ((unsigned)hg[2 * j] << 16);

  // clamp-folded D-blur weights, f32, transposed: wlT[d][dout]
  for (int o = 0; o < DD; ++o)
    for (int d = 0; d < DD; ++d) {
      float w = 0.f;
      for (int k = 0; k < 11; ++k) {
        int j = o + k - 5;
        j = j < 0 ? 0 : (j > 15 ? 15 : j);
        if (j == d) w += g[k];
      }
      ka.wlT[d * DD + o] = w;
    }

  zero_acc_k<<<1, 64, 0, stream>>>(acc);
  fused_k<<<NB * 1024, NTHR, 0, stream>>>(pred, gt, acc, ka);
  final_k<<<1, 1, 0, stream>>>(acc, (float*)d_out);
}

// Round 9
// 245.259 us; speedup vs baseline: 2.5601x; 1.0291x over previous
//
#include <hip/hip_runtime.h>
#include <cmath>

// PSNR + 3D-SSIM, pred/gt (N=4, C=16->D, H=512, W=512) f32.
// R17 = R16 (154.5us: R11 dot2 structure + XCD swizzle; fetch-theory
// refuted -- FETCH dropped 3.3x, dur barely moved; VALU 53% dominates) +
// two VALU/occupancy fixes, everything else byte-identical:
//  1) D-accumulate on packed f32: channel-paired accumulators
//     A01={a0,a1}, A23={a2,a3}, __builtin_elementwise_fma on float2 ->
//     v_pk_fma_f32 (full-rate dual f32). 64 fma/slice -> 32 pk_fma/slice.
//  2) Wave-uniform W-column parity (bijective remap wy=(wv>>1)*8+(ln>>3),
//     wx=2*(ln&7)+(wv&1)): cw[] table -> readfirstlane -> SGPRs, ~6 VGPRs
//     freed; 132 -> ~126 total regs <= 128 -> 4 waves/SIMD (was 3).
// No hard launch_bounds cap, no mega-unroll (R10/R15 spill lessons).

#define NB 4
#define DD 16
#define HH 512
#define WW 512
#define SLICE (HH * WW)
#define VOL (DD * SLICE)
#define C1F 0.0001f
#define C2F 0.0009f

#define TH 16
#define TW 16
#define SCOLS 26            // staged cols (TW+10)
#define NRP 13              // staged row-pairs ((TH+10)/2)
#define PW 14               // uint4 words per col-parity plane (13 + pad)
#define PLSTR 28            // row-pair stride (2 planes)
#define SDW (NRP * PLSTR)   // 364 uint4 = 5824 B
#define TMW (TH * PW)       // 224 uint4 = 3584 B
#define NTHR 256
#define SIT (NRP * SCOLS)   // 338 stage items per slice
#define XTRA (SIT - NTHR)   // 82
#define HITEMS 104          // 8 out-row-pairs x 13 col-pairs

typedef _Float16 h2v __attribute__((ext_vector_type(2)));
typedef float f32x2 __attribute__((ext_vector_type(2)));

struct KArg {
  unsigned ge[6], go[6];   // f16x2 tap-pair coeffs, even/odd phase (renorm'd)
  float wlT[DD * DD];      // wlT[d*16+dout] = clamp-folded D weight (f32)
};

__device__ inline float dot2h(unsigned a, unsigned b, float c) {
#if __has_builtin(__builtin_amdgcn_fdot2)
  return __builtin_amdgcn_fdot2(__builtin_bit_cast(h2v, a),
                                __builtin_bit_cast(h2v, b), c, false);
#else
  h2v av = __builtin_bit_cast(h2v, a), bv = __builtin_bit_cast(h2v, b);
  return fmaf((float)av.y, (float)bv.y, fmaf((float)av.x, (float)bv.x, c));
#endif
}
__device__ inline unsigned pkh(float a, float b) {
  return __builtin_bit_cast(unsigned, __builtin_amdgcn_cvt_pkrtz(a, b));
}
__device__ inline int iclamp(int v, int lo, int hi) {
  return v < lo ? lo : (v > hi ? hi : v);
}

__device__ inline float block_sum256(float v) {
#pragma unroll
  for (int o = 32; o > 0; o >>= 1) v += __shfl_down(v, o, 64);
  __shared__ float r[4];
  if ((threadIdx.x & 63) == 0) r[threadIdx.x >> 6] = v;
  __syncthreads();
  float out = 0.f;
  if (threadIdx.x == 0) {
#pragma unroll
    for (int i = 0; i < 4; ++i) out += r[i];
  }
  __syncthreads();
  return out;
}

__global__ void zero_acc_k(float* acc) {
  if (threadIdx.x < 8) acc[threadIdx.x] = 0.f;
}

__global__ __launch_bounds__(NTHR, 3) void fused_k(
    const float* __restrict__ pred, const float* __restrict__ gt,
    float* __restrict__ acc, KArg ka) {
  __shared__ uint4 sd[SDW];    // single-buffered staged slice
  __shared__ uint4 tmp[TMW];   // H-blurred

  // XCD-aware bijective swizzle (kept from R16: FETCH 257->78 MB)
  int b0 = blockIdx.x;
  int b = (b0 & 7) * ((NB * 1024) >> 3) + (b0 >> 3);
  int tile = b & 1023;               // 32 h-tiles x 32 w-tiles
  int n = b >> 10;
  int th0 = (tile >> 5) * TH;
  int tw0 = (tile & 31) * TW;
  int t = threadIdx.x;

  // ---- stage metadata, slot 0 (item t, always < 338)
  int rp0 = t / SCOLS, x0 = t - rp0 * SCOLS;
  int gx0 = iclamp(tw0 + x0 - 5, 0, WW - 1);
  int go0a = iclamp(th0 + 2 * rp0 - 5, 0, HH - 1) * WW + gx0;
  int go0b = iclamp(th0 + 2 * rp0 - 4, 0, HH - 1) * WW + gx0;
  int w0i = (2 * rp0 + (x0 & 1)) * PW + (x0 >> 1);
  bool ox0 = (x0 >= 5) && (x0 < 5 + TW);
  float o0a = (ox0 && rp0 >= 3 && rp0 <= 10) ? 1.f : 0.f;  // row 2rp-5 owned
  float o0b = (ox0 && rp0 >= 2 && rp0 <= 9) ? 1.f : 0.f;   // row 2rp-4 owned
  // slot 1 (items 256..337 -> threads 174..255)
  int i1 = t + XTRA;
  bool has2 = (i1 >= NTHR);
  int rp1 = i1 / SCOLS, x1 = i1 - rp1 * SCOLS;
  int gx1 = iclamp(tw0 + x1 - 5, 0, WW - 1);
  int go1a = iclamp(th0 + 2 * rp1 - 5, 0, HH - 1) * WW + gx1;
  int go1b = iclamp(th0 + 2 * rp1 - 4, 0, HH - 1) * WW + gx1;
  int w1i = (2 * rp1 + (x1 & 1)) * PW + (x1 >> 1);
  bool ox1 = (x1 >= 5) && (x1 < 5 + TW);
  float o1a = (ox1 && rp1 >= 3 && rp1 <= 10) ? 1.f : 0.f;
  float o1b = (ox1 && rp1 >= 2 && rp1 <= 9) ? 1.f : 0.f;

  // ---- H metadata: item = (out-row-pair hm, col-pair hcp), m-minor
  bool hasH = (t < HITEMS);
  int hm = t & 7, hcp = t >> 3;
  int hrd = hm * PLSTR + hcp;        // plane0 read base (tap J adds J*PLSTR)
  int hwr = (2 * hm) * PW + hcp;     // row 2m write (+PW for row 2m+1)

  // ---- W metadata: wave-uniform column parity (bijective remap)
  // wy = (wv>>1)*8 + (ln>>3), wx = 2*(ln&7) + (wv&1)
  int ln = t & 63, wv4 = t >> 6;
  int wpar = __builtin_amdgcn_readfirstlane(wv4 & 1);
  int wy = (wv4 >> 1) * 8 + (ln >> 3);
  int wxh = ln & 7;                  // wx >> 1
  int wrd = wy * PW + wxh;
  unsigned cw[6];                    // wave-uniform -> SGPRs
#pragma unroll
  for (int J = 0; J < 6; ++J) cw[J] = wpar ? ka.go[J] : ka.ge[J];

  const float* pb = pred + (size_t)n * VOL;
  const float* qb = gt + (size_t)n * VOL;

  // prefetch slice 0
  float p0a = pb[go0a], p0b = pb[go0b], q0a = qb[go0a], q0b = qb[go0b];
  float p1a = 0.f, p1b = 0.f, q1a = 0.f, q1b = 0.f;
  if (has2) { p1a = pb[go1a]; p1b = pb[go1b]; q1a = qb[go1a]; q1b = qb[go1b]; }

  float psnr = 0.f;
  f32x2 A01[DD], A23[DD];            // {a0,a1} and {a2,a3} channel pairs
#pragma unroll
  for (int j = 0; j < DD; ++j) {
    A01[j] = (f32x2){0.f, 0.f};
    A23[j] = (f32x2){0.f, 0.f};
  }

#pragma unroll 1
  for (int d = 0; d < DD; ++d) {
    // ---- stage slice d (f16 row-pair packed, AoS uint4)
    {
      float SA = p0a + q0a, DA = p0a - q0a;
      float SB = p0b + q0b, DB = p0b - q0b;
      float dA = DA * DA, dB = DB * DB;
      psnr = fmaf(o0a, dA, psnr);
      psnr = fmaf(o0b, dB, psnr);
      sd[w0i] = make_uint4(pkh(SA, SB), pkh(DA, DB),
                           pkh(SA * SA, SB * SB), pkh(dA, dB));
    }
    if (has2) {
      float SA = p1a + q1a, DA = p1a - q1a;
      float SB = p1b + q1b, DB = p1b - q1b;
      float dA = DA * DA, dB = DB * DB;
      psnr = fmaf(o1a, dA, psnr);
      psnr = fmaf(o1b, dB, psnr);
      sd[w1i] = make_uint4(pkh(SA, SB), pkh(DA, DB),
                           pkh(SA * SA, SB * SB), pkh(dA, dB));
    }
    __syncthreads();   // B1: sd ready; also fences tmp vs prev iter's W reads

    // prefetch slice d+1 (hides under H+W; consumed next iter after B2+W)
    if (d < DD - 1) {
      const float* P = pb + (size_t)(d + 1) * SLICE;
      const float* Q = qb + (size_t)(d + 1) * SLICE;
      p0a = P[go0a]; p0b = P[go0b]; q0a = Q[go0a]; q0b = Q[go0b];
      if (has2) { p1a = P[go1a]; p1b = P[go1b]; q1a = Q[go1a]; q1b = Q[go1b]; }
    }

    // ---- H-blur (vertical), fused row parities: 12 b128 reads -> 2 writes
    if (hasH) {
      float e0[4] = {0, 0, 0, 0}, e1[4] = {0, 0, 0, 0};   // row 2m, col 2cp / 2cp+1
      float r0[4] = {0, 0, 0, 0}, r1[4] = {0, 0, 0, 0};   // row 2m+1
#pragma unroll
      for (int J = 0; J < 6; ++J) {
        uint4 ve = sd[hrd + J * PLSTR];        // col 2cp,  row-pair m+J
        uint4 vo = sd[hrd + J * PLSTR + PW];   // col 2cp+1
        unsigned cge = ka.ge[J], cgo = ka.go[J];
        e0[0] = dot2h(cge, ve.x, e0[0]); e0[1] = dot2h(cge, ve.y, e0[1]);
        e0[2] = dot2h(cge, ve.z, e0[2]); e0[3] = dot2h(cge, ve.w, e0[3]);
        r0[0] = dot2h(cgo, ve.x, r0[0]); r0[1] = dot2h(cgo, ve.y, r0[1]);
        r0[2] = dot2h(cgo, ve.z, r0[2]); r0[3] = dot2h(cgo, ve.w, r0[3]);
        e1[0] = dot2h(cge, vo.x, e1[0]); e1[1] = dot2h(cge, vo.y, e1[1]);
        e1[2] = dot2h(cge, vo.z, e1[2]); e1[3] = dot2h(cge, vo.w, e1[3]);
        r1[0] = dot2h(cgo, vo.x, r1[0]); r1[1] = dot2h(cgo, vo.y, r1[1]);
        r1[2] = dot2h(cgo, vo.z, r1[2]); r1[3] = dot2h(cgo, vo.w, r1[3]);
      }
      tmp[hwr] = make_uint4(pkh(e0[0], e1[0]), pkh(e0[1], e1[1]),
                            pkh(e0[2], e1[2]), pkh(e0[3], e1[3]));
      tmp[hwr + PW] = make_uint4(pkh(r0[0], r1[0]), pkh(r0[1], r1[1]),
                                 pkh(r0[2], r1[2]), pkh(r0[3], r1[3]));
    }
    __syncthreads();   // B2: tmp ready; also separates H's sd reads from the
                       // NEXT iteration's stage writes (single buffer safe)

    // ---- W-blur at owned px: 6 b128 reads, 24 dot2
    float w0 = 0.f, w1 = 0.f, w2 = 0.f, w3 = 0.f;
#pragma unroll
    for (int J = 0; J < 6; ++J) {
      uint4 v = tmp[wrd + J];
      w0 = dot2h(cw[J], v.x, w0); w1 = dot2h(cw[J], v.y, w1);
      w2 = dot2h(cw[J], v.z, w2); w3 = dot2h(cw[J], v.w, w3);
    }
    // ---- D-accumulate: packed f32 (v_pk_fma_f32), weights SGPR-uniform
    const float* wl = ka.wlT + d * DD;
    f32x2 W01 = {w0, w1}, W23 = {w2, w3};
#pragma unroll
    for (int o = 0; o < DD; ++o) {
      float w = wl[o];
      f32x2 ws = {w, w};
      A01[o] = __builtin_elementwise_fma(ws, W01, A01[o]);
      A23[o] = __builtin_elementwise_fma(ws, W23, A23[o]);
    }
  }

  // ---- SSIM over the 16 douts of this px
  float ssum = 0.f;
#pragma unroll
  for (int j = 0; j < DD; ++j) {
    float Sb = A01[j].x, Db = A01[j].y, B1 = A23[j].x, B2 = A23[j].y;
    float SS = Sb * Sb, DDm = Db * Db;
    float m12_2 = (SS - DDm) * 0.5f;     // 2*mu1*mu2
    float msq   = (SS + DDm) * 0.5f;     // mu1^2 + mu2^2
    float Epq   = (B1 - B2) * 0.25f;     // E[pq]
    float Esum  = (B1 + B2) * 0.5f;      // E[p^2+q^2]
    float sig12_2 = 2.f * Epq - m12_2;   // 2*sigma12
    float svar    = Esum - msq;          // sigma1^2 + sigma2^2
    float num = (m12_2 + C1F) * (sig12_2 + C2F);
    float den = (msq + C1F) * (svar + C2F);
    ssum += num / den;
  }
  float bs = block_sum256(ssum);
  if (t == 0) atomicAdd(&acc[4 + n], bs);
  float bp = block_sum256(psnr);
  if (t == 0) atomicAdd(&acc[n], bp);
}

__global__ void final_k(const float* __restrict__ acc, float* __restrict__ out) {
  if (threadIdx.x == 0 && blockIdx.x == 0) {
    double psnr = 0.0, ssim = 0.0;
    for (int n = 0; n < NB; ++n) {
      double mse = (double)acc[n] / (double)VOL;
      psnr += 10.0 * log10(1.0 / mse);
      ssim += (double)acc[4 + n] / (double)VOL;
    }
    out[0] = (float)psnr;
    out[1] = (float)ssim;
    out[2] = (float)NB;
  }
}

// host f32 -> f16 (round-to-nearest-even)
static unsigned short f2h(float f) {
  union { float f; unsigned u; } v; v.f = f;
  unsigned u = v.u;
  unsigned s = (u >> 16) & 0x8000u;
  int e = (int)((u >> 23) & 0xff) - 127 + 15;
  unsigned m = u & 0x7fffffu;
  if (e <= 0) return (unsigned short)s;
  if (e >= 31) return (unsigned short)(s | 0x7c00u);
  unsigned h = ((unsigned)e << 10) | (m >> 13);
  unsigned rem = m & 0x1fffu;
  if (rem > 0x1000u || (rem == 0x1000u && (h & 1u))) h++;
  return (unsigned short)(s | h);
}
// host f16 -> f32 (normals + zero)
static float h2f(unsigned short h) {
  unsigned se = (h >> 10) & 0x1f, m = h & 0x3ffu, s = ((unsigned)h & 0x8000u) << 16;
  union { unsigned u; float f; } v;
  if (se == 0) { v.u = s; return v.f; }
  v.u = s | ((se - 15 + 127) << 23) | (m << 13);
  return v.f;
}

extern "C" void kernel_launch(void* const* d_in, const int* in_sizes, int n_in,
                              void* d_out, int out_size, void* d_ws, size_t ws_size,
                              hipStream_t stream) {
  const float* pred = (const float*)d_in[0];
  const float* gt = (const float*)d_in[1];
  float* acc = (float*)d_ws;    // 8 floats

  double tt[11], s = 0.0;
  for (int i = 0; i < 11; ++i) {
    double x = i - 5;
    tt[i] = exp(-(x * x) / 4.5);
    s += tt[i];
  }
  float g[11];
  for (int i = 0; i < 11; ++i) g[i] = (float)(tt[i] / s);

  // f16 taps renormalized so the f16 values sum exactly to 1
  unsigned short hg[11];
  for (int i = 0; i < 11; ++i) hg[i] = f2h(g[i]);
  for (int pass = 0; pass < 3; ++pass) {
    double sum = 0.0;
    for (int i = 0; i < 11; ++i) sum += (double)h2f(hg[i]);
    hg[5] = f2h((float)((double)h2f(hg[5]) + (1.0 - sum)));
  }

  KArg ka;
  // even phase: (g0,g1)(g2,g3)(g4,g5)(g6,g7)(g8,g9)(g10,0)
  for (int j = 0; j < 5; ++j)
    ka.ge[j] = (unsigned)hg[2 * j] | ((unsigned)hg[2 * j + 1] << 16);
  ka.ge[5] = (unsigned)hg[10];
  // odd phase: (0,g0)(g1,g2)(g3,g4)(g5,g6)(g7,g8)(g9,g10)
  ka.go[0] = ((unsigned)hg[0]) << 16;
  for (int j = 1; j < 6; ++j)
    ka.go[j] = (unsigned)hg[2 * j - 1] | ((unsigned)hg[2 * j] << 16);

  // clamp-folded D-blur weights, f32, transposed: wlT[d][dout]
  for (int o = 0; o < DD; ++o)
    for (int d = 0; d < DD; ++d) {
      float w = 0.f;
      for (int k = 0; k < 11; ++k) {
        int j = o + k - 5;
        j = j < 0 ? 0 : (j > 15 ? 15 : j);
        if (j == d) w += g[k];
      }
      ka.wlT[d * DD + o] = w;
    }

  zero_acc_k<<<1, 64, 0, stream>>>(acc);
  fused_k<<<NB * 1024, NTHR, 0, stream>>>(pred, gt, acc, ka);
  final_k<<<1, 1, 0, stream>>>(acc, (float*)d_out);
}